// Round 17
// baseline (86750.781 us; speedup 1.0000x reference)
//
#include <hip/hip_runtime.h>
#include <stdint.h>
#include <math.h>

#define TSTEPS 256
#define BATCH  256
#define OBS_D  512
#define FEATD  512
#define NACT   15
#define HDIM   528
#define HB     (HDIM*BATCH)   /* 135168 */
#define NBLK   594u

/* ---- compact ws layout (~5.8 MB), plain [k][B] acts ---- */
#define OFF_ND    0
#define OFF_FLAG  65536
#define OFF_CNT   65540      /* global barrier arrival counter */
#define OFF_GEN   65544      /* global barrier generation */
#define ALW_BYTES 262208
#define SB        91952
#define FXT       (SB)
#define FH0       (FXT + 4*HB)
#define FH1       (FH0 + 2*HB)
#define FC0       (FH1 + 2*HB)
#define FC1       (FC0 + HB)

/* ALW float offsets */
#define DBS0   0
#define DBS1   2112
#define DBENC  4224
#define DHW    4736
#define DHB    13184
#define DALW_N 13200

/* out float offsets */
#define OUT_POL   0
#define OUT_BASE  983040
#define OUT_ACT   1048576
#define OUT_H     1114112
#define OUT_C     1384448

__device__ __forceinline__ float sigf_(float x){ return 1.0f/(1.0f+expf(-x)); }

__device__ __forceinline__ uint32_t rotl32_(uint32_t x, uint32_t d){
  return (x<<d)|(x>>(32u-d));
}

/* JAX partitionable threefry 32-bit: bits = out0 ^ out1. [VERIFIED R5-R16] */
__device__ double gumbel_for(uint32_t idx){
  uint32_t x0 = 0u, x1 = idx;
  const uint32_t k0 = 0u, k1 = 1u;
  const uint32_t ks[3] = {k0, k1, 0x1BD11BDAu ^ k0 ^ k1};
  x0 += ks[0]; x1 += ks[1];
  const uint32_t R0[4] = {13u,15u,26u,6u}, R1[4] = {17u,29u,16u,24u};
  #pragma unroll
  for (int g=0; g<5; ++g){
    const uint32_t* r = (g&1) ? R1 : R0;
    #pragma unroll
    for (int j=0;j<4;++j){ x0 += x1; x1 = rotl32_(x1, r[j]); x1 ^= x0; }
    x0 += ks[(g+1)%3];
    x1 += ks[(g+2)%3] + (uint32_t)(g+1);
  }
  const uint32_t bits = x0 ^ x1;
  float u = __uint_as_float((bits>>9) | 0x3f800000u) - 1.0f;
  const float TINY = 1.17549435e-38f;
  u = u * (1.0f - TINY) + TINY;
  u = fmaxf(TINY, u);
  return -log(-log((double)u));
}

__global__ void zero_kernel(float* __restrict__ p, int n){
  int i = blockIdx.x*256 + threadIdx.x;
  if (i < n) p[i] = 0.0f;
}

__global__ void detect_term_kernel(const void* __restrict__ term, int* __restrict__ flag){
  __shared__ int s_nf, s_nb, s_ni;
  if (threadIdx.x==0){ s_nf=0; s_nb=0; s_ni=0; }
  __syncthreads();
  const uint8_t*  pb = (const uint8_t*)term;
  const uint32_t* pw = (const uint32_t*)term;
  int nf=0, nb=0, ni=0;
  for (int i=threadIdx.x; i<16384; i+=256){
    uint32_t v = pw[i];
    if (v == 0x3F800000u) nf++;
    if (v == 1u) ni++;
  }
  for (int o=threadIdx.x; o<65536; o+=256){
    if ((o&3) && pb[o]) nb++;
  }
  if (nf) atomicAdd(&s_nf, nf);
  if (nb) atomicAdd(&s_nb, nb);
  if (ni) atomicAdd(&s_ni, ni);
  __syncthreads();
  if (threadIdx.x==0){
    flag[0] = (s_nf>0) ? 2 : ((s_nb>0) ? 0 : ((s_ni>0) ? 1 : 0));
  }
}

__global__ void nd_kernel(const void* __restrict__ term, const int* __restrict__ flag,
                          float* __restrict__ nd){
  int i = blockIdx.x*256 + threadIdx.x;
  if (i >= TSTEPS*BATCH) return;
  int f = flag[0];
  bool done;
  if (f == 0)      done = ((const uint8_t*)term)[i] != 0;
  else if (f == 1) done = ((const int*)term)[i] != 0;
  else             done = ((const float*)term)[i] != 0.0f;
  nd[i] = done ? 0.0f : 1.0f;
}

__global__ void prep_small_kernel(float* __restrict__ alw,
    const float* __restrict__ bih0, const float* __restrict__ bhh0,
    const float* __restrict__ bih1, const float* __restrict__ bhh1,
    const float* __restrict__ benc,
    const float* __restrict__ Wpol, const float* __restrict__ bpol,
    const float* __restrict__ Wbase, const float* __restrict__ bbase){
  int i = blockIdx.x*256 + threadIdx.x;
  if (i >= DALW_N) return;
  if (i < 2112)            alw[DBS0 + i] = bih0[i] + bhh0[i];
  else if (i < 4224)       { int j=i-2112; alw[DBS1 + j] = bih1[j] + bhh1[j]; }
  else if (i < 4736)       { int j=i-4224; alw[DBENC + j] = benc[j]; }
  else if (i < 13184)      { int j=i-4736; int r=j/HDIM, k=j%HDIM;
                             alw[DHW + j] = (r<NACT ? Wpol[r*HDIM+k] : Wbase[k]); }
  else                     { int j=i-13184; alw[DHB + j] = (j<NACT ? bpol[j] : bbase[0]); }
}

/* Device-wide generation barrier. Leader-only atomics; spin via coherent
   (AGENT-scope) pure loads; watchdog poisons gen so failure is fast-visible. */
__device__ __forceinline__ void gbar(unsigned* cnt, unsigned* gen, unsigned idx){
  __threadfence();                 /* release: this block's stores visible */
  __syncthreads();
  if (threadIdx.x == 0){
    unsigned arr = atomicAdd(cnt, 1u) + 1u;
    if (arr == idx * NBLK){
      atomicAdd(gen, 1u);
    } else {
      unsigned it = 0;
      while (__hip_atomic_load(gen, __ATOMIC_RELAXED, __HIP_MEMORY_SCOPE_AGENT) < idx){
        __builtin_amdgcn_s_sleep(2);
        if (++it > (1u<<22)){ atomicMax(gen, 0x40000000u); break; }
      }
    }
  }
  __syncthreads();
  __threadfence();                 /* acquire: invalidate stale cached acts */
}

/* LSTM compute using pre-staged LDS weight slab [8][1056] (wih row | whh row).
   Identical arithmetic to R15-champ: bias -> x k-asc -> masked h k-asc. */
__device__ __forceinline__ void lstm_compute(
    const float* __restrict__ smem, int jt, int step,
    const float* __restrict__ srcA, const float* __restrict__ srcB,
    const float* __restrict__ bsum, const float* __restrict__ nd,
    float* __restrict__ cbuf, float* __restrict__ hout, int b)
{
  const int j0 = jt*2;
  const float ndv = nd[step*BATCH + b];
  float acc[8];
  #pragma unroll
  for (int c=0;c<8;++c) acc[c] = bsum[(c>>1)*HDIM + j0 + (c&1)];

  {
    const float* a = srcA + b;
    #pragma unroll 2
    for (int kq=0; kq<132; ++kq){
      float xv[4];
      #pragma unroll
      for (int u=0;u<4;++u) xv[u] = a[(size_t)(kq*4+u)*BATCH];
      #pragma unroll
      for (int c=0;c<8;++c){
        const float4 w4 = *(const float4*)(smem + c*1056 + kq*4);
        acc[c] = fmaf(w4.x, xv[0], acc[c]);
        acc[c] = fmaf(w4.y, xv[1], acc[c]);
        acc[c] = fmaf(w4.z, xv[2], acc[c]);
        acc[c] = fmaf(w4.w, xv[3], acc[c]);
      }
    }
  }
  {
    const float* bb = srcB + b;
    #pragma unroll 2
    for (int kq=0; kq<132; ++kq){
      float hv[4];
      #pragma unroll
      for (int u=0;u<4;++u) hv[u] = bb[(size_t)(kq*4+u)*BATCH] * ndv;
      #pragma unroll
      for (int c=0;c<8;++c){
        const float4 w4 = *(const float4*)(smem + c*1056 + 528 + kq*4);
        acc[c] = fmaf(w4.x, hv[0], acc[c]);
        acc[c] = fmaf(w4.y, hv[1], acc[c]);
        acc[c] = fmaf(w4.z, hv[2], acc[c]);
        acc[c] = fmaf(w4.w, hv[3], acc[c]);
      }
    }
  }

  #pragma unroll
  for (int jj=0;jj<2;++jj){
    const float gi=acc[0+jj], gf=acc[2+jj], gg=acc[4+jj], go=acc[6+jj];
    const int idx=(j0+jj)*BATCH+b;
    const float cold = cbuf[idx]*ndv;
    const float cn = sigf_(gf)*cold + sigf_(gi)*tanhf(gg);
    const float hn = sigf_(go)*tanhf(cn);
    cbuf[idx]=cn; hout[idx]=hn;
  }
}

/* Persistent kernel: stage weights once, then 260 steps with SW grid barrier.
   Roles: [0,264)=L0@t, [264,528)=L1@t-1, [528,592)=enc@t+2,
   592=enc extras @t+2, 593=head+sample @t-2. */
__global__ __launch_bounds__(256, 3) void persist_kernel(
  const float* __restrict__ obs, const int* __restrict__ lastAct,
  const float* __restrict__ reward,
  const float* __restrict__ wenc,
  const float* __restrict__ wih0, const float* __restrict__ whh0,
  const float* __restrict__ wih1, const float* __restrict__ whh1,
  float* __restrict__ ws, float* __restrict__ alw,
  float* __restrict__ out)
{
  __shared__ float smem[8448];
  const int bid = blockIdx.x;
  const int b = threadIdx.x;
  unsigned* cnt = (unsigned*)(ws + OFF_CNT);
  unsigned* gen = (unsigned*)(ws + OFF_GEN);
  float* nd = ws + OFF_ND;
  float* xT = ws + FXT;
  float* h0 = ws + FH0;
  float* h1 = ws + FH1;
  float* c0 = ws + FC0;
  float* c1 = ws + FC1;

  /* one-time weight staging for LSTM blocks */
  if (bid < 528){
    const int lay = (bid < 264) ? 0 : 1;
    const int jt  = lay ? bid-264 : bid;
    const int j0  = jt*2;
    const float* wih = lay ? wih1 : wih0;
    const float* whh = lay ? whh1 : whh0;
    for (int i=b; i<2112; i+=256){
      const int c  = i/264;
      const int r4 = i - c*264;
      const int col = (c>>1)*HDIM + j0 + (c&1);
      float4 v;
      if (r4 < 132) v = *(const float4*)(wih + (size_t)col*HDIM + r4*4);
      else          v = *(const float4*)(whh + (size_t)col*HDIM + (r4-132)*4);
      *(float4*)(smem + c*1056 + r4*4) = v;
    }
  }
  __syncthreads();

  unsigned bar = 0;
  for (int t = -2; t <= 257; ++t){
    if (bid < 264) {                       /* layer 0 @ t */
      if (t >= 0 && t <= 255)
        lstm_compute(smem, bid, t,
                     xT + (size_t)(t&3)*HB,
                     h0 + (size_t)((t+1)&1)*HB,
                     alw + DBS0, nd, c0,
                     h0 + (size_t)(t&1)*HB, b);
    } else if (bid < 528) {                /* layer 1 @ t-1 */
      const int s = t - 1;
      if (s >= 0 && s <= 255)
        lstm_compute(smem, bid-264, s,
                     h0 + (size_t)(s&1)*HB,
                     h1 + (size_t)((s+1)&1)*HB,
                     alw + DBS1, nd, c1,
                     h1 + (size_t)(s&1)*HB, b);
    } else if (bid < 593) {                /* encoder @ t+2 */
      const int te = t + 2;
      if (te >= 0 && te <= 255){
        float* xs = xT + (size_t)(te&3)*HB;
        if (bid < 592) {
          float (*lx)[257] = (float(*)[257])smem;
          const int e = bid - 528;
          const int f0 = e*8;
          float acc[8];
          const float* wrow[8];
          #pragma unroll
          for (int c=0;c<8;++c){ acc[c]=alw[DBENC+f0+c]; wrow[c]=wenc+(size_t)(f0+c)*OBS_D; }
          const int r0 = threadIdx.x>>3;
          const int kk = (threadIdx.x&7)<<2;
          for (int kc=0; kc<OBS_D; kc+=32){
            __syncthreads();
            #pragma unroll
            for (int rr=0; rr<256; rr+=32){
              const float4 v = *(const float4*)(obs + ((size_t)te*BATCH + (r0+rr))*OBS_D + kc + kk);
              lx[kk+0][r0+rr]=v.x; lx[kk+1][r0+rr]=v.y; lx[kk+2][r0+rr]=v.z; lx[kk+3][r0+rr]=v.w;
            }
            __syncthreads();
            #pragma unroll 4
            for (int k2=0;k2<32;++k2){
              const float xv = lx[k2][b];
              #pragma unroll
              for (int c=0;c<8;++c) acc[c] = fmaf(xv, wrow[c][kc+k2], acc[c]);
            }
          }
          #pragma unroll
          for (int c=0;c<8;++c) xs[(size_t)(f0+c)*BATCH + b] = fmaxf(acc[c], 0.0f);
        } else {
          const float r = reward[te*BATCH + b];
          xs[(size_t)FEATD*BATCH + b] = fminf(fmaxf(r, -1.0f), 1.0f);
          const int la = lastAct[te*BATCH + b];
          #pragma unroll
          for (int a2=0; a2<NACT; ++a2)
            xs[(size_t)(FEATD+1+a2)*BATCH + b] = (a2==la) ? 1.0f : 0.0f;
        }
      }
    } else {                               /* head + sampling @ t-2 */
      const int s = t - 2;
      if (s >= 0 && s <= 255){
        const float* hsrc = h1 + (size_t)(s&1)*HB;
        float acc[16];
        #pragma unroll
        for (int c=0;c<16;++c) acc[c]=alw[DHB+c];
        const float* hb = hsrc + b;
        #pragma unroll 4
        for (int k=0;k<HDIM;++k){
          const float hv = hb[(size_t)k*BATCH];
          #pragma unroll
          for (int c=0;c<16;++c) acc[c] = fmaf(hv, alw[DHW + (size_t)c*HDIM + k], acc[c]);
        }
        const int row = s*BATCH + b;
        #pragma unroll
        for (int c=0;c<15;++c) out[OUT_POL + (size_t)row*NACT + c] = acc[c];
        out[OUT_BASE + row] = acc[15];
        double best = -1.0e300; int bi = 0;
        #pragma unroll
        for (int a2=0; a2<NACT; ++a2){
          const double v = (double)acc[a2] + gumbel_for((uint32_t)(row*NACT + a2));
          if (v > best){ best = v; bi = a2; }
        }
        out[OUT_ACT + row] = (float)bi;
      }
    }
    gbar(cnt, gen, ++bar);
  }
}

__global__ void finalize_kernel(const float* __restrict__ ws, float* __restrict__ out){
  int i = blockIdx.x*256 + threadIdx.x;
  if (i >= 2*HB) return;
  const int l = i / HB;
  const int r = i % HB;
  const int bq = r / HDIM;
  const int j  = r % HDIM;
  const float* hf = ws + (l==0 ? FH0 : FH1) + HB;   /* step-255 parity = 1 */
  const float* cf = ws + (l==0 ? FC0 : FC1);
  out[OUT_H + i] = hf[(size_t)j*BATCH + bq];
  out[OUT_C + i] = cf[(size_t)j*BATCH + bq];
}

extern "C" void kernel_launch(void* const* d_in, const int* in_sizes, int n_in,
                              void* d_out, int out_size, void* d_ws, size_t ws_size,
                              hipStream_t stream) {
  const float* obs     = (const float*)d_in[0];
  const int*   lastAct = (const int*)  d_in[1];
  const float* reward  = (const float*)d_in[2];
  const void*  term    =               d_in[3];
  const float* Wenc    = (const float*)d_in[4];
  const float* benc    = (const float*)d_in[5];
  const float* wih0    = (const float*)d_in[6];
  const float* whh0    = (const float*)d_in[7];
  const float* bih0    = (const float*)d_in[8];
  const float* bhh0    = (const float*)d_in[9];
  const float* wih1    = (const float*)d_in[10];
  const float* whh1    = (const float*)d_in[11];
  const float* bih1    = (const float*)d_in[12];
  const float* bhh1    = (const float*)d_in[13];
  const float* Wpol    = (const float*)d_in[14];
  const float* bpol    = (const float*)d_in[15];
  const float* Wbase   = (const float*)d_in[16];
  const float* bbase   = (const float*)d_in[17];
  float*  ws   = (float*)d_ws;
  int*    flag = (int*)(ws + OFF_FLAG);
  float*  alw  = (float*)((char*)d_ws + ALW_BYTES);
  float*  out  = (float*)d_out;

  /* zero h/c state + barrier counters every call (determinism) */
  {
    const int nz = 6*HB;
    zero_kernel<<<(nz+255)/256, 256, 0, stream>>>(ws + FH0, nz);
    zero_kernel<<<1, 64, 0, stream>>>(ws + OFF_CNT, 8);
  }
  detect_term_kernel<<<1, 256, 0, stream>>>(term, flag);
  nd_kernel<<<(TSTEPS*BATCH+255)/256, 256, 0, stream>>>(term, flag, ws + OFF_ND);
  prep_small_kernel<<<(DALW_N+255)/256, 256, 0, stream>>>(alw,
      bih0, bhh0, bih1, bhh1, benc, Wpol, bpol, Wbase, bbase);

  persist_kernel<<<NBLK, 256, 0, stream>>>(
      obs, lastAct, reward,
      Wenc, wih0, whh0, wih1, whh1,
      ws, alw, out);

  finalize_kernel<<<(2*HB+255)/256, 256, 0, stream>>>(ws, out);
}

// Round 18
// 34696.603 us; speedup vs baseline: 2.5003x; 2.5003x over previous
//
#include <hip/hip_runtime.h>
#include <stdint.h>
#include <math.h>

#define TSTEPS 256
#define BATCH  256
#define OBS_D  512
#define FEATD  512
#define NACT   15
#define HDIM   528
#define HB     (HDIM*BATCH)   /* 135168 */

/* ---- compact ws layout (~5.8 MB), plain [k][B] acts ---- */
#define OFF_ND    0
#define OFF_FLAG  65536
#define ALW_BYTES 262208
#define SB        91952
#define FXT       (SB)
#define FH0       (FXT + 4*HB)
#define FH1       (FH0 + 2*HB)
#define FC0       (FH1 + 2*HB)
#define FC1       (FC0 + HB)

/* ALW float offsets */
#define DBS0   0
#define DBS1   2112
#define DBENC  4224
#define DHW    4736
#define DHB    13184
#define DALW_N 13200

/* out float offsets */
#define OUT_POL   0
#define OUT_BASE  983040
#define OUT_ACT   1048576
#define OUT_H     1114112
#define OUT_C     1384448

__device__ __forceinline__ float sigf_(float x){ return 1.0f/(1.0f+expf(-x)); }

__device__ __forceinline__ uint32_t rotl32_(uint32_t x, uint32_t d){
  return (x<<d)|(x>>(32u-d));
}

/* JAX partitionable threefry 32-bit: bits = out0 ^ out1. [VERIFIED R5-R17] */
__device__ double gumbel_for(uint32_t idx){
  uint32_t x0 = 0u, x1 = idx;
  const uint32_t k0 = 0u, k1 = 1u;
  const uint32_t ks[3] = {k0, k1, 0x1BD11BDAu ^ k0 ^ k1};
  x0 += ks[0]; x1 += ks[1];
  const uint32_t R0[4] = {13u,15u,26u,6u}, R1[4] = {17u,29u,16u,24u};
  #pragma unroll
  for (int g=0; g<5; ++g){
    const uint32_t* r = (g&1) ? R1 : R0;
    #pragma unroll
    for (int j=0;j<4;++j){ x0 += x1; x1 = rotl32_(x1, r[j]); x1 ^= x0; }
    x0 += ks[(g+1)%3];
    x1 += ks[(g+2)%3] + (uint32_t)(g+1);
  }
  const uint32_t bits = x0 ^ x1;
  float u = __uint_as_float((bits>>9) | 0x3f800000u) - 1.0f;
  const float TINY = 1.17549435e-38f;
  u = u * (1.0f - TINY) + TINY;
  u = fmaxf(TINY, u);
  return -log(-log((double)u));
}

__global__ void zero_kernel(float* __restrict__ p, int n){
  int i = blockIdx.x*256 + threadIdx.x;
  if (i < n) p[i] = 0.0f;
}

__global__ void detect_term_kernel(const void* __restrict__ term, int* __restrict__ flag){
  __shared__ int s_nf, s_nb, s_ni;
  if (threadIdx.x==0){ s_nf=0; s_nb=0; s_ni=0; }
  __syncthreads();
  const uint8_t*  pb = (const uint8_t*)term;
  const uint32_t* pw = (const uint32_t*)term;
  int nf=0, nb=0, ni=0;
  for (int i=threadIdx.x; i<16384; i+=256){
    uint32_t v = pw[i];
    if (v == 0x3F800000u) nf++;
    if (v == 1u) ni++;
  }
  for (int o=threadIdx.x; o<65536; o+=256){
    if ((o&3) && pb[o]) nb++;
  }
  if (nf) atomicAdd(&s_nf, nf);
  if (nb) atomicAdd(&s_nb, nb);
  if (ni) atomicAdd(&s_ni, ni);
  __syncthreads();
  if (threadIdx.x==0){
    flag[0] = (s_nf>0) ? 2 : ((s_nb>0) ? 0 : ((s_ni>0) ? 1 : 0));
  }
}

__global__ void nd_kernel(const void* __restrict__ term, const int* __restrict__ flag,
                          float* __restrict__ nd){
  int i = blockIdx.x*256 + threadIdx.x;
  if (i >= TSTEPS*BATCH) return;
  int f = flag[0];
  bool done;
  if (f == 0)      done = ((const uint8_t*)term)[i] != 0;
  else if (f == 1) done = ((const int*)term)[i] != 0;
  else             done = ((const float*)term)[i] != 0.0f;
  nd[i] = done ? 0.0f : 1.0f;
}

__global__ void prep_small_kernel(float* __restrict__ alw,
    const float* __restrict__ bih0, const float* __restrict__ bhh0,
    const float* __restrict__ bih1, const float* __restrict__ bhh1,
    const float* __restrict__ benc,
    const float* __restrict__ Wpol, const float* __restrict__ bpol,
    const float* __restrict__ Wbase, const float* __restrict__ bbase){
  int i = blockIdx.x*256 + threadIdx.x;
  if (i >= DALW_N) return;
  if (i < 2112)            alw[DBS0 + i] = bih0[i] + bhh0[i];
  else if (i < 4224)       { int j=i-2112; alw[DBS1 + j] = bih1[j] + bhh1[j]; }
  else if (i < 4736)       { int j=i-4224; alw[DBENC + j] = benc[j]; }
  else if (i < 13184)      { int j=i-4736; int r=j/HDIM, k=j%HDIM;
                             alw[DHW + j] = (r<NACT ? Wpol[r*HDIM+k] : Wbase[k]); }
  else                     { int j=i-13184; alw[DHB + j] = (j<NACT ? bpol[j] : bbase[0]); }
}

/* LSTM j-tile (2 j, 8 gate cols) with PASS-SPLIT waves:
   512 threads = {pass0: x-dot waves (b=tid&255), pass1: h-dot waves}.
   Weight slab [8][1056] in LDS (shared); h-waves write partial acc to LDS;
   x-waves combine (bias + x-sum) + h-sum, then gate epilogue.
   Act streams (srcA by pass0, srcB by pass1) read CONCURRENTLY. */
__device__ __forceinline__ void lstm_split(
    float* __restrict__ smw,    /* 8448 floats: weight slab */
    float* __restrict__ smr,    /* 8*257 floats: h partials */
    int jt, int step, const float* __restrict__ srcA, const float* __restrict__ srcB,
    const float* __restrict__ wih, const float* __restrict__ whh,
    const float* __restrict__ bsum,
    const float* __restrict__ nd, float* __restrict__ cbuf, float* __restrict__ hout,
    int tid)
{
  const int pass = tid >> 8;
  const int b = tid & 255;
  const int j0 = jt*2;

  /* stage weights: 2112 float4s over 512 threads */
  for (int i = tid; i < 2112; i += 512){
    const int c  = i / 264;
    const int r4 = i - c*264;
    const int col = (c>>1)*HDIM + j0 + (c&1);
    float4 v;
    if (r4 < 132) v = *(const float4*)(wih + (size_t)col*HDIM + r4*4);
    else          v = *(const float4*)(whh + (size_t)col*HDIM + (r4-132)*4);
    *(float4*)(smw + c*1056 + r4*4) = v;
  }
  __syncthreads();

  const float ndv = nd[step*BATCH + b];
  float acc[8];

  if (pass == 0){
    /* x-dot: bias + sum_k wA[c][k]*x[k] (k ascending) */
    #pragma unroll
    for (int c=0;c<8;++c) acc[c] = bsum[(c>>1)*HDIM + j0 + (c&1)];
    const float* a = srcA + b;
    #pragma unroll 4
    for (int kq=0; kq<132; ++kq){
      float xv[4];
      #pragma unroll
      for (int u=0;u<4;++u) xv[u] = a[(size_t)(kq*4+u)*BATCH];
      #pragma unroll
      for (int c=0;c<8;++c){
        const float4 w4 = *(const float4*)(smw + c*1056 + kq*4);
        acc[c] = fmaf(w4.x, xv[0], acc[c]);
        acc[c] = fmaf(w4.y, xv[1], acc[c]);
        acc[c] = fmaf(w4.z, xv[2], acc[c]);
        acc[c] = fmaf(w4.w, xv[3], acc[c]);
      }
    }
  } else {
    /* h-dot partial: sum_k wB[c][k]*h[k]*nd (k ascending), from 0 */
    #pragma unroll
    for (int c=0;c<8;++c) acc[c] = 0.0f;
    const float* bb = srcB + b;
    #pragma unroll 4
    for (int kq=0; kq<132; ++kq){
      float hv[4];
      #pragma unroll
      for (int u=0;u<4;++u) hv[u] = bb[(size_t)(kq*4+u)*BATCH] * ndv;
      #pragma unroll
      for (int c=0;c<8;++c){
        const float4 w4 = *(const float4*)(smw + c*1056 + 528 + kq*4);
        acc[c] = fmaf(w4.x, hv[0], acc[c]);
        acc[c] = fmaf(w4.y, hv[1], acc[c]);
        acc[c] = fmaf(w4.z, hv[2], acc[c]);
        acc[c] = fmaf(w4.w, hv[3], acc[c]);
      }
    }
    #pragma unroll
    for (int c=0;c<8;++c) smr[c*257 + b] = acc[c];
  }
  __syncthreads();

  if (pass == 0){
    #pragma unroll
    for (int c=0;c<8;++c) acc[c] += smr[c*257 + b];
    #pragma unroll
    for (int jj=0;jj<2;++jj){
      const float gi=acc[0+jj], gf=acc[2+jj], gg=acc[4+jj], go=acc[6+jj];
      const int idx=(j0+jj)*BATCH+b;
      const float cold = cbuf[idx]*ndv;
      const float cn = sigf_(gf)*cold + sigf_(gi)*tanhf(gg);
      const float hn = sigf_(go)*tanhf(cn);
      cbuf[idx]=cn; hout[idx]=hn;
    }
  }
}

/* Skewed pipeline, 594 blocks x 512 threads: [0,264)=L0@t, [264,528)=L1@t-1,
   [528,592)=enc@t+2, 592=enc extras @t+2, 593=head+sample @t-2 */
__global__ __launch_bounds__(512) void step_kernel(
  const float* __restrict__ obs, const int* __restrict__ lastAct,
  const float* __restrict__ reward,
  const float* __restrict__ wenc,
  const float* __restrict__ wih0, const float* __restrict__ whh0,
  const float* __restrict__ wih1, const float* __restrict__ whh1,
  float* __restrict__ ws, float* __restrict__ alw,
  float* __restrict__ out, int t)
{
  __shared__ float smw[8448];
  __shared__ float smr[8*257];
  const int bid = blockIdx.x;
  const int tid = threadIdx.x;
  float* nd = ws + OFF_ND;
  float* xT = ws + FXT;
  float* h0 = ws + FH0;
  float* h1 = ws + FH1;
  float* c0 = ws + FC0;
  float* c1 = ws + FC1;

  if (bid < 264) {                       /* layer 0 @ t */
    if (t < 0 || t > 255) return;
    lstm_split(smw, smr, bid, t,
               xT + (size_t)(t&3)*HB,
               h0 + (size_t)((t+1)&1)*HB,
               wih0, whh0, alw + DBS0, nd, c0,
               h0 + (size_t)(t&1)*HB, tid);
  } else if (bid < 528) {                /* layer 1 @ t-1 */
    const int s = t - 1;
    if (s < 0 || s > 255) return;
    lstm_split(smw, smr, bid-264, s,
               h0 + (size_t)(s&1)*HB,
               h1 + (size_t)((s+1)&1)*HB,
               wih1, whh1, alw + DBS1, nd, c1,
               h1 + (size_t)(s&1)*HB, tid);
  } else if (bid < 593) {                /* encoder @ t+2 */
    const int te = t + 2;
    if (te < 0 || te > 255) return;
    float* xs = xT + (size_t)(te&3)*HB;
    if (bid < 592) {
      float (*lx)[257] = (float(*)[257])smw;   /* 32 x 257 = 8224 <= 8448 */
      const int e = bid - 528;
      const int f0 = e*8;
      float acc[8];
      const float* wrow[8];
      #pragma unroll
      for (int c=0;c<8;++c){ acc[c]=alw[DBENC+f0+c]; wrow[c]=wenc+(size_t)(f0+c)*OBS_D; }
      const int r0 = tid>>3;            /* 0..63 */
      const int kk = (tid&7)<<2;
      const int b = tid & 255;
      for (int kc=0; kc<OBS_D; kc+=32){
        __syncthreads();
        #pragma unroll
        for (int rr=0; rr<256; rr+=64){
          const float4 v = *(const float4*)(obs + ((size_t)te*BATCH + (r0+rr))*OBS_D + kc + kk);
          lx[kk+0][r0+rr]=v.x; lx[kk+1][r0+rr]=v.y; lx[kk+2][r0+rr]=v.z; lx[kk+3][r0+rr]=v.w;
        }
        __syncthreads();
        if (tid < 256){
          #pragma unroll 4
          for (int k2=0;k2<32;++k2){
            const float xv = lx[k2][b];
            #pragma unroll
            for (int c=0;c<8;++c) acc[c] = fmaf(xv, wrow[c][kc+k2], acc[c]);
          }
        }
      }
      if (tid < 256){
        #pragma unroll
        for (int c=0;c<8;++c) xs[(size_t)(f0+c)*BATCH + tid] = fmaxf(acc[c], 0.0f);
      }
    } else {
      if (tid < 256){
        const float r = reward[te*BATCH + tid];
        xs[(size_t)FEATD*BATCH + tid] = fminf(fmaxf(r, -1.0f), 1.0f);
        const int la = lastAct[te*BATCH + tid];
        #pragma unroll
        for (int a2=0; a2<NACT; ++a2)
          xs[(size_t)(FEATD+1+a2)*BATCH + tid] = (a2==la) ? 1.0f : 0.0f;
      }
    }
  } else {                               /* head + sampling @ t-2 */
    const int s = t - 2;
    if (s < 0 || s > 255 || tid >= 256) return;
    const int b = tid;
    const float* hsrc = h1 + (size_t)(s&1)*HB;
    float acc[16];
    #pragma unroll
    for (int c=0;c<16;++c) acc[c]=alw[DHB+c];
    const float* hb = hsrc + b;
    #pragma unroll 4
    for (int k=0;k<HDIM;++k){
      const float hv = hb[(size_t)k*BATCH];
      #pragma unroll
      for (int c=0;c<16;++c) acc[c] = fmaf(hv, alw[DHW + (size_t)c*HDIM + k], acc[c]);
    }
    const int row = s*BATCH + b;
    #pragma unroll
    for (int c=0;c<15;++c) out[OUT_POL + (size_t)row*NACT + c] = acc[c];
    out[OUT_BASE + row] = acc[15];
    double best = -1.0e300; int bi = 0;
    #pragma unroll
    for (int a2=0; a2<NACT; ++a2){
      const double v = (double)acc[a2] + gumbel_for((uint32_t)(row*NACT + a2));
      if (v > best){ best = v; bi = a2; }
    }
    out[OUT_ACT + row] = (float)bi;
  }
}

__global__ void finalize_kernel(const float* __restrict__ ws, float* __restrict__ out){
  int i = blockIdx.x*256 + threadIdx.x;
  if (i >= 2*HB) return;
  const int l = i / HB;
  const int r = i % HB;
  const int bq = r / HDIM;
  const int j  = r % HDIM;
  const float* hf = ws + (l==0 ? FH0 : FH1) + HB;   /* step-255 parity = 1 */
  const float* cf = ws + (l==0 ? FC0 : FC1);
  out[OUT_H + i] = hf[(size_t)j*BATCH + bq];
  out[OUT_C + i] = cf[(size_t)j*BATCH + bq];
}

extern "C" void kernel_launch(void* const* d_in, const int* in_sizes, int n_in,
                              void* d_out, int out_size, void* d_ws, size_t ws_size,
                              hipStream_t stream) {
  const float* obs     = (const float*)d_in[0];
  const int*   lastAct = (const int*)  d_in[1];
  const float* reward  = (const float*)d_in[2];
  const void*  term    =               d_in[3];
  const float* Wenc    = (const float*)d_in[4];
  const float* benc    = (const float*)d_in[5];
  const float* wih0    = (const float*)d_in[6];
  const float* whh0    = (const float*)d_in[7];
  const float* bih0    = (const float*)d_in[8];
  const float* bhh0    = (const float*)d_in[9];
  const float* wih1    = (const float*)d_in[10];
  const float* whh1    = (const float*)d_in[11];
  const float* bih1    = (const float*)d_in[12];
  const float* bhh1    = (const float*)d_in[13];
  const float* Wpol    = (const float*)d_in[14];
  const float* bpol    = (const float*)d_in[15];
  const float* Wbase   = (const float*)d_in[16];
  const float* bbase   = (const float*)d_in[17];
  float*  ws   = (float*)d_ws;
  int*    flag = (int*)(ws + OFF_FLAG);
  float*  alw  = (float*)((char*)d_ws + ALW_BYTES);
  float*  out  = (float*)d_out;

  /* zero h/c state (6*HB floats at FH0) every call */
  {
    const int nz = 6*HB;
    zero_kernel<<<(nz+255)/256, 256, 0, stream>>>(ws + FH0, nz);
  }
  detect_term_kernel<<<1, 256, 0, stream>>>(term, flag);
  nd_kernel<<<(TSTEPS*BATCH+255)/256, 256, 0, stream>>>(term, flag, ws + OFF_ND);
  prep_small_kernel<<<(DALW_N+255)/256, 256, 0, stream>>>(alw,
      bih0, bhh0, bih1, bhh1, benc, Wpol, bpol, Wbase, bbase);

  for (int t = -2; t <= 257; ++t) {
    step_kernel<<<594, 512, 0, stream>>>(
      obs, lastAct, reward,
      Wenc, wih0, whh0, wih1, whh1,
      ws, alw, out, t);
  }
  finalize_kernel<<<(2*HB+255)/256, 256, 0, stream>>>(ws, out);
}

// Round 19
// 26783.148 us; speedup vs baseline: 3.2390x; 1.2955x over previous
//
#include <hip/hip_runtime.h>
#include <stdint.h>
#include <math.h>

#define TSTEPS 256
#define BATCH  256
#define OBS_D  512
#define FEATD  512
#define NACT   15
#define HDIM   528
#define HB     (HDIM*BATCH)
#define PK     544              /* padded K per half (528 + 16 zeros) */

typedef __attribute__((ext_vector_type(8))) short short8v;
typedef __attribute__((ext_vector_type(4))) short short4v;
typedef __attribute__((ext_vector_type(4))) float float4v;

/* ---- ws BYTE offsets (total 5,296,128 B < proven-safe 5.77MB) ---- */
#define OFF_ND_B     0            /* f32 [T][B] */
#define OFF_FLAG_B   262144
#define OFF_ALW_B    262208       /* f32 x 13200 */
#define XP_B         315392       /* x planes: 3 slots x {hi,lo} [256][544] bf16 */
#define SLOT_B       557056       /* 2 planes */
#define PL_B         278528       /* one plane */
#define H0P_B        1986560      /* h0 planes: 2 par x {hi,lo} */
#define H1P_B        3100672
#define C0_B         4214784     /* f32 [j][B] */
#define C1_B         4755456
#define WS_END_B     5296128

/* ALW float offsets */
#define DBS0   0
#define DBS1   2112
#define DBENC  4224
#define DHW    4736
#define DHB    13184
#define DALW_N 13200

/* out float offsets */
#define OUT_POL   0
#define OUT_BASE  983040
#define OUT_ACT   1048576
#define OUT_H     1114112
#define OUT_C     1384448

__device__ __forceinline__ float sigf_(float x){ return 1.0f/(1.0f+expf(-x)); }

__device__ __forceinline__ unsigned short f2bf(float f){
  unsigned u = __float_as_uint(f);
  unsigned r = (u + 0x7FFFu + ((u>>16)&1u)) >> 16;   /* RNE */
  return (unsigned short)r;
}
__device__ __forceinline__ float bf2f(unsigned short s){
  return __uint_as_float(((unsigned)s)<<16);
}

__device__ __forceinline__ uint32_t rotl32_(uint32_t x, uint32_t d){
  return (x<<d)|(x>>(32u-d));
}

/* JAX partitionable threefry 32-bit: bits = out0 ^ out1. [VERIFIED R5-R18] */
__device__ double gumbel_for(uint32_t idx){
  uint32_t x0 = 0u, x1 = idx;
  const uint32_t k0 = 0u, k1 = 1u;
  const uint32_t ks[3] = {k0, k1, 0x1BD11BDAu ^ k0 ^ k1};
  x0 += ks[0]; x1 += ks[1];
  const uint32_t R0[4] = {13u,15u,26u,6u}, R1[4] = {17u,29u,16u,24u};
  #pragma unroll
  for (int g=0; g<5; ++g){
    const uint32_t* r = (g&1) ? R1 : R0;
    #pragma unroll
    for (int j=0;j<4;++j){ x0 += x1; x1 = rotl32_(x1, r[j]); x1 ^= x0; }
    x0 += ks[(g+1)%3];
    x1 += ks[(g+2)%3] + (uint32_t)(g+1);
  }
  const uint32_t bits = x0 ^ x1;
  float u = __uint_as_float((bits>>9) | 0x3f800000u) - 1.0f;
  const float TINY = 1.17549435e-38f;
  u = u * (1.0f - TINY) + TINY;
  u = fmaxf(TINY, u);
  return -log(-log((double)u));
}

__global__ void zero_kernel(float* __restrict__ p, int n){
  int i = blockIdx.x*256 + threadIdx.x;
  if (i < n) p[i] = 0.0f;
}

__global__ void detect_term_kernel(const void* __restrict__ term, int* __restrict__ flag){
  __shared__ int s_nf, s_nb, s_ni;
  if (threadIdx.x==0){ s_nf=0; s_nb=0; s_ni=0; }
  __syncthreads();
  const uint8_t*  pb = (const uint8_t*)term;
  const uint32_t* pw = (const uint32_t*)term;
  int nf=0, nb=0, ni=0;
  for (int i=threadIdx.x; i<16384; i+=256){
    uint32_t v = pw[i];
    if (v == 0x3F800000u) nf++;
    if (v == 1u) ni++;
  }
  for (int o=threadIdx.x; o<65536; o+=256){
    if ((o&3) && pb[o]) nb++;
  }
  if (nf) atomicAdd(&s_nf, nf);
  if (nb) atomicAdd(&s_nb, nb);
  if (ni) atomicAdd(&s_ni, ni);
  __syncthreads();
  if (threadIdx.x==0){
    flag[0] = (s_nf>0) ? 2 : ((s_nb>0) ? 0 : ((s_ni>0) ? 1 : 0));
  }
}

__global__ void nd_kernel(const void* __restrict__ term, const int* __restrict__ flag,
                          float* __restrict__ nd){
  int i = blockIdx.x*256 + threadIdx.x;
  if (i >= TSTEPS*BATCH) return;
  int f = flag[0];
  bool done;
  if (f == 0)      done = ((const uint8_t*)term)[i] != 0;
  else if (f == 1) done = ((const int*)term)[i] != 0;
  else             done = ((const float*)term)[i] != 0.0f;
  nd[i] = done ? 0.0f : 1.0f;
}

__global__ void prep_small_kernel(float* __restrict__ alw,
    const float* __restrict__ bih0, const float* __restrict__ bhh0,
    const float* __restrict__ bih1, const float* __restrict__ bhh1,
    const float* __restrict__ benc,
    const float* __restrict__ Wpol, const float* __restrict__ bpol,
    const float* __restrict__ Wbase, const float* __restrict__ bbase){
  int i = blockIdx.x*256 + threadIdx.x;
  if (i >= DALW_N) return;
  if (i < 2112)            alw[DBS0 + i] = bih0[i] + bhh0[i];
  else if (i < 4224)       { int j=i-2112; alw[DBS1 + j] = bih1[j] + bhh1[j]; }
  else if (i < 4736)       { int j=i-4224; alw[DBENC + j] = benc[j]; }
  else if (i < 13184)      { int j=i-4736; int r=j/HDIM, k=j%HDIM;
                             alw[DHW + j] = (r<NACT ? Wpol[r*HDIM+k] : Wbase[k]); }
  else                     { int j=i-13184; alw[DHB + j] = (j<NACT ? bpol[j] : bbase[0]); }
}

/* MFMA LSTM block: 16 j x 4 gates x 64 b. Waves = gates. Virtual A = [Wih|pad|Whh|pad]
   (16 rows/gate x 1088 K), staged per-64-K-chunk to LDS as bf16 hi/lo (double-buffered).
   B = [firstHalf | secondHalf] act planes bf16 hi/lo; second half masked by nd (0/1 exact).
   3-term split MFMA; cell update fused via LDS gate exchange. */
__device__ __forceinline__ void lstm_mfma(
    unsigned short* __restrict__ smem_u,
    int j16, int nb, int step,
    const unsigned short* __restrict__ bAh, const unsigned short* __restrict__ bAl,
    const unsigned short* __restrict__ bBh, const unsigned short* __restrict__ bBl,
    unsigned short* __restrict__ oHh, unsigned short* __restrict__ oHl,
    const float* __restrict__ wih, const float* __restrict__ whh,
    const float* __restrict__ bsum, const float* __restrict__ nd,
    float* __restrict__ cbuf, int tid)
{
  const int w = tid>>6, l = tid&63;
  const int j0 = j16*16, n0 = nb*64;
  const int sr = tid&63, kq = tid>>6;
  const int gate = sr>>4, jr = j0 + (sr&15);
  const float* rih = wih + (size_t)(gate*528 + jr)*528;
  const float* rhh = whh + (size_t)(gate*528 + jr)*528;
  const short8v zv = {0,0,0,0,0,0,0,0};

  bool ndm[4];
  #pragma unroll
  for (int s=0;s<4;++s) ndm[s] = nd[step*BATCH + n0 + s*16 + (l&15)] != 0.0f;

  float4v acc[4];
  #pragma unroll
  for (int s=0;s<4;++s) acc[s] = (float4v){0.f,0.f,0.f,0.f};

  auto STAGE = [&](int cc, int bsel){
    const int vk0 = cc*64 + kq*16;
    float v[16];
    if (vk0 < 528){
      const float4* p = (const float4*)(rih + vk0);
      #pragma unroll
      for (int q=0;q<4;++q){ float4 x = p[q]; v[q*4]=x.x; v[q*4+1]=x.y; v[q*4+2]=x.z; v[q*4+3]=x.w; }
    } else if (vk0 < 544){
      #pragma unroll
      for (int i=0;i<16;++i) v[i]=0.0f;
    } else if (vk0 < 1072){
      const float4* p = (const float4*)(rhh + (vk0-544));
      #pragma unroll
      for (int q=0;q<4;++q){ float4 x = p[q]; v[q*4]=x.x; v[q*4+1]=x.y; v[q*4+2]=x.z; v[q*4+3]=x.w; }
    } else {
      #pragma unroll
      for (int i=0;i<16;++i) v[i]=0.0f;
    }
    short8v hA, hB, lA, lB;
    #pragma unroll
    for (int i=0;i<8;++i){
      unsigned short hb = f2bf(v[i]);
      hA[i] = (short)hb; lA[i] = (short)f2bf(v[i] - bf2f(hb));
    }
    #pragma unroll
    for (int i=0;i<8;++i){
      unsigned short hb = f2bf(v[8+i]);
      hB[i] = (short)hb; lB[i] = (short)f2bf(v[8+i] - bf2f(hb));
    }
    unsigned short* dh = smem_u + bsel*9216 + sr*72 + kq*16;
    *(short8v*)(dh)          = hA;
    *(short8v*)(dh + 8)      = hB;
    *(short8v*)(dh + 4608)   = lA;
    *(short8v*)(dh + 4616)   = lB;
  };

  auto KSTEP = [&](int ks){
    const unsigned short* sl = smem_u + ((ks>>1)&1)*9216;
    const int aoff = (16*w + (l&15))*72 + (ks&1)*32 + ((l>>4)<<3);
    const short8v ah = *(const short8v*)(sl + aoff);
    const short8v al = *(const short8v*)(sl + 4608 + aoff);
    const bool second = (ks >= 17);
    const int kin = (second ? (ks-17)*32 : ks*32) + ((l>>4)<<3);
    const unsigned short* ph  = second ? bBh : bAh;
    const unsigned short* pl2 = second ? bBl : bAl;
    #pragma unroll
    for (int s=0;s<4;++s){
      const int n = n0 + s*16 + (l&15);
      short8v bh = *(const short8v*)(ph  + (size_t)n*PK + kin);
      short8v bl = *(const short8v*)(pl2 + (size_t)n*PK + kin);
      if (second && !ndm[s]){ bh = zv; bl = zv; }
      acc[s] = __builtin_amdgcn_mfma_f32_16x16x32_bf16(ah, bh, acc[s], 0,0,0);
      acc[s] = __builtin_amdgcn_mfma_f32_16x16x32_bf16(ah, bl, acc[s], 0,0,0);
      acc[s] = __builtin_amdgcn_mfma_f32_16x16x32_bf16(al, bh, acc[s], 0,0,0);
    }
  };

  STAGE(0, 0);
  __syncthreads();
  #pragma unroll 1
  for (int cc=0; cc<17; ++cc){
    if (cc < 16) STAGE(cc+1, (cc+1)&1);
    KSTEP(2*cc); KSTEP(2*cc+1);
    __syncthreads();
  }

  /* gate exchange: gates[4][16][68] f32 (aliases slab; post-barrier) */
  float* gf = (float*)smem_u;
  #pragma unroll
  for (int s=0;s<4;++s){
    #pragma unroll
    for (int r2=0;r2<4;++r2)
      gf[w*1088 + (((l>>4)<<2)+r2)*68 + s*16 + (l&15)] = acc[s][r2];
  }
  __syncthreads();

  /* epilogue: thread = (b = n0 + tid&63, 4 consecutive j) */
  const int bl = tid&63, j4 = tid>>6;
  const int b = n0 + bl;
  const float ndv = nd[step*BATCH + b];
  short4v hv, lv;
  #pragma unroll
  for (int jj=0;jj<4;++jj){
    const int jloc = j4*4 + jj, j = j0 + jloc;
    const float gi = gf[0*1088 + jloc*68 + bl] + bsum[j];
    const float gff= gf[1*1088 + jloc*68 + bl] + bsum[528 + j];
    const float gg = gf[2*1088 + jloc*68 + bl] + bsum[1056 + j];
    const float go = gf[3*1088 + jloc*68 + bl] + bsum[1584 + j];
    const int idx = j*BATCH + b;
    const float cold = cbuf[idx]*ndv;
    const float cn = sigf_(gff)*cold + sigf_(gi)*tanhf(gg);
    const float hn = sigf_(go)*tanhf(cn);
    cbuf[idx] = cn;
    const unsigned short hb = f2bf(hn);
    hv[jj] = (short)hb;
    lv[jj] = (short)f2bf(hn - bf2f(hb));
  }
  *(short4v*)(oHh + (size_t)b*PK + j0 + j4*4) = hv;
  *(short4v*)(oHl + (size_t)b*PK + j0 + j4*4) = lv;
}

/* Grid 330: [0,132)=L0@t, [132,264)=L1@t-1, [264,328)=enc@t+2,
   328=extras@t+2, 329=head+sample@t-2 */
__global__ __launch_bounds__(256) void step_kernel(
  const float* __restrict__ obs, const int* __restrict__ lastAct,
  const float* __restrict__ reward,
  const float* __restrict__ wenc,
  const float* __restrict__ wih0, const float* __restrict__ whh0,
  const float* __restrict__ wih1, const float* __restrict__ whh1,
  float* __restrict__ ws, float* __restrict__ alw,
  float* __restrict__ out, int t)
{
  __shared__ unsigned short smem_u[18432];   /* 36.9 KB */
  const int bid = blockIdx.x;
  const int tid = threadIdx.x;
  float* nd = (float*)((char*)ws + OFF_ND_B);
  char* wsc = (char*)ws;

  if (bid < 264){
    const int layer = (bid < 132) ? 0 : 1;
    const int rr = layer ? bid-132 : bid;
    const int step = layer ? t-1 : t;
    if (step < 0 || step > 255) return;
    const int j16 = rr>>2, nb = rr&3;
    const unsigned short *bAh,*bAl,*bBh,*bBl; unsigned short *oHh,*oHl;
    const float *wih,*whh,*bsum; float* cbuf;
    if (layer == 0){
      const int sl = step%3, pp = (step+1)&1, po = step&1;
      bAh = (const unsigned short*)(wsc + XP_B + sl*SLOT_B);
      bAl = (const unsigned short*)(wsc + XP_B + sl*SLOT_B + PL_B);
      bBh = (const unsigned short*)(wsc + H0P_B + pp*SLOT_B);
      bBl = (const unsigned short*)(wsc + H0P_B + pp*SLOT_B + PL_B);
      oHh = (unsigned short*)(wsc + H0P_B + po*SLOT_B);
      oHl = (unsigned short*)(wsc + H0P_B + po*SLOT_B + PL_B);
      wih = wih0; whh = whh0; bsum = alw + DBS0;
      cbuf = (float*)(wsc + C0_B);
    } else {
      const int pa = step&1, pb2 = (step+1)&1;
      bAh = (const unsigned short*)(wsc + H0P_B + pa*SLOT_B);
      bAl = (const unsigned short*)(wsc + H0P_B + pa*SLOT_B + PL_B);
      bBh = (const unsigned short*)(wsc + H1P_B + pb2*SLOT_B);
      bBl = (const unsigned short*)(wsc + H1P_B + pb2*SLOT_B + PL_B);
      oHh = (unsigned short*)(wsc + H1P_B + pa*SLOT_B);
      oHl = (unsigned short*)(wsc + H1P_B + pa*SLOT_B + PL_B);
      wih = wih1; whh = whh1; bsum = alw + DBS1;
      cbuf = (float*)(wsc + C1_B);
    }
    lstm_mfma(smem_u, j16, nb, step, bAh, bAl, bBh, bBl, oHh, oHl,
              wih, whh, bsum, nd, cbuf, tid);
  } else if (bid < 328){                 /* encoder @ t+2 */
    const int te = t + 2;
    if (te < 0 || te > 255) return;
    const int sl = te%3;
    unsigned short* xh = (unsigned short*)(wsc + XP_B + sl*SLOT_B);
    unsigned short* xl = (unsigned short*)(wsc + XP_B + sl*SLOT_B + PL_B);
    float (*lx)[257] = (float(*)[257])smem_u;
    const int e = bid - 264;
    const int f0 = e*8;
    const int b = tid;
    float acc[8];
    const float* wrow[8];
    #pragma unroll
    for (int c=0;c<8;++c){ acc[c]=alw[DBENC+f0+c]; wrow[c]=wenc+(size_t)(f0+c)*OBS_D; }
    const int r0 = tid>>3;
    const int kk = (tid&7)<<2;
    for (int kc=0; kc<OBS_D; kc+=32){
      __syncthreads();
      #pragma unroll
      for (int rr2=0; rr2<256; rr2+=32){
        const float4 v = *(const float4*)(obs + ((size_t)te*BATCH + (r0+rr2))*OBS_D + kc + kk);
        lx[kk+0][r0+rr2]=v.x; lx[kk+1][r0+rr2]=v.y; lx[kk+2][r0+rr2]=v.z; lx[kk+3][r0+rr2]=v.w;
      }
      __syncthreads();
      #pragma unroll 4
      for (int k2=0;k2<32;++k2){
        const float xv = lx[k2][b];
        #pragma unroll
        for (int c=0;c<8;++c) acc[c] = fmaf(xv, wrow[c][kc+k2], acc[c]);
      }
    }
    short8v hv, lv;
    #pragma unroll
    for (int c=0;c<8;++c){
      const float v = fmaxf(acc[c], 0.0f);
      const unsigned short hb = f2bf(v);
      hv[c] = (short)hb; lv[c] = (short)f2bf(v - bf2f(hb));
    }
    *(short8v*)(xh + (size_t)b*PK + f0) = hv;
    *(short8v*)(xl + (size_t)b*PK + f0) = lv;
  } else if (bid == 328){                /* extras @ t+2 */
    const int te = t + 2;
    if (te < 0 || te > 255) return;
    const int sl = te%3;
    unsigned short* xh = (unsigned short*)(wsc + XP_B + sl*SLOT_B);
    unsigned short* xl = (unsigned short*)(wsc + XP_B + sl*SLOT_B + PL_B);
    const int b = tid;
    float vals[16];
    const float r = reward[te*BATCH + b];
    vals[0] = fminf(fmaxf(r, -1.0f), 1.0f);
    const int la = lastAct[te*BATCH + b];
    #pragma unroll
    for (int a2=0; a2<NACT; ++a2) vals[1+a2] = (a2==la) ? 1.0f : 0.0f;
    short8v hv0, lv0, hv1, lv1;
    #pragma unroll
    for (int i=0;i<8;++i){
      unsigned short hb = f2bf(vals[i]);
      hv0[i]=(short)hb; lv0[i]=(short)f2bf(vals[i]-bf2f(hb));
    }
    #pragma unroll
    for (int i=0;i<8;++i){
      unsigned short hb = f2bf(vals[8+i]);
      hv1[i]=(short)hb; lv1[i]=(short)f2bf(vals[8+i]-bf2f(hb));
    }
    *(short8v*)(xh + (size_t)b*PK + 512) = hv0;
    *(short8v*)(xh + (size_t)b*PK + 520) = hv1;
    *(short8v*)(xl + (size_t)b*PK + 512) = lv0;
    *(short8v*)(xl + (size_t)b*PK + 520) = lv1;
  } else {                               /* head + sampling @ t-2 */
    const int s = t - 2;
    if (s < 0 || s > 255) return;
    const int pa = s&1;
    const unsigned short* hh = (const unsigned short*)(wsc + H1P_B + pa*SLOT_B);
    const unsigned short* hl = (const unsigned short*)(wsc + H1P_B + pa*SLOT_B + PL_B);
    const int b = tid;
    float acc[16];
    #pragma unroll
    for (int c=0;c<16;++c) acc[c]=alw[DHB+c];
    for (int kc=0; kc<66; ++kc){
      const short8v H = *(const short8v*)(hh + (size_t)b*PK + kc*8);
      const short8v L = *(const short8v*)(hl + (size_t)b*PK + kc*8);
      #pragma unroll
      for (int u=0;u<8;++u){
        const float hv = bf2f((unsigned short)H[u]) + bf2f((unsigned short)L[u]);
        const int k = kc*8+u;
        #pragma unroll
        for (int c=0;c<16;++c) acc[c] = fmaf(hv, alw[DHW + (size_t)c*HDIM + k], acc[c]);
      }
    }
    const int row = s*BATCH + b;
    #pragma unroll
    for (int c=0;c<15;++c) out[OUT_POL + (size_t)row*NACT + c] = acc[c];
    out[OUT_BASE + row] = acc[15];
    double best = -1.0e300; int bi = 0;
    #pragma unroll
    for (int a2=0; a2<NACT; ++a2){
      const double v = (double)acc[a2] + gumbel_for((uint32_t)(row*NACT + a2));
      if (v > best){ best = v; bi = a2; }
    }
    out[OUT_ACT + row] = (float)bi;
  }
}

__global__ void finalize_kernel(const float* __restrict__ ws, float* __restrict__ out){
  int i = blockIdx.x*256 + threadIdx.x;
  if (i >= 2*HB) return;
  const char* wsc = (const char*)ws;
  const int l = i / HB;
  const int r = i % HB;
  const int bq = r / HDIM;
  const int j  = r % HDIM;
  /* final parity = 255&1 = 1 */
  const unsigned short* hh = (const unsigned short*)(wsc + (l==0?H0P_B:H1P_B) + 1*SLOT_B);
  const unsigned short* hl = hh + PL_B/2;
  const float* cf = (const float*)(wsc + (l==0?C0_B:C1_B));
  out[OUT_H + i] = bf2f(hh[(size_t)bq*PK + j]) + bf2f(hl[(size_t)bq*PK + j]);
  out[OUT_C + i] = cf[(size_t)j*BATCH + bq];
}

extern "C" void kernel_launch(void* const* d_in, const int* in_sizes, int n_in,
                              void* d_out, int out_size, void* d_ws, size_t ws_size,
                              hipStream_t stream) {
  const float* obs     = (const float*)d_in[0];
  const int*   lastAct = (const int*)  d_in[1];
  const float* reward  = (const float*)d_in[2];
  const void*  term    =               d_in[3];
  const float* Wenc    = (const float*)d_in[4];
  const float* benc    = (const float*)d_in[5];
  const float* wih0    = (const float*)d_in[6];
  const float* whh0    = (const float*)d_in[7];
  const float* bih0    = (const float*)d_in[8];
  const float* bhh0    = (const float*)d_in[9];
  const float* wih1    = (const float*)d_in[10];
  const float* whh1    = (const float*)d_in[11];
  const float* bih1    = (const float*)d_in[12];
  const float* bhh1    = (const float*)d_in[13];
  const float* Wpol    = (const float*)d_in[14];
  const float* bpol    = (const float*)d_in[15];
  const float* Wbase   = (const float*)d_in[16];
  const float* bbase   = (const float*)d_in[17];
  float*  ws   = (float*)d_ws;
  int*    flag = (int*)((char*)d_ws + OFF_FLAG_B);
  float*  alw  = (float*)((char*)d_ws + OFF_ALW_B);
  float*  out  = (float*)d_out;

  /* zero all planes + c (also zeroes k-pads and initial h/c state) */
  {
    const int nz = (WS_END_B - XP_B)/4;
    zero_kernel<<<(nz+255)/256, 256, 0, stream>>>(ws + XP_B/4, nz);
  }
  detect_term_kernel<<<1, 256, 0, stream>>>(term, flag);
  nd_kernel<<<(TSTEPS*BATCH+255)/256, 256, 0, stream>>>(term, flag, (float*)((char*)d_ws + OFF_ND_B));
  prep_small_kernel<<<(DALW_N+255)/256, 256, 0, stream>>>(alw,
      bih0, bhh0, bih1, bhh1, benc, Wpol, bpol, Wbase, bbase);

  for (int t = -2; t <= 257; ++t) {
    step_kernel<<<330, 256, 0, stream>>>(
      obs, lastAct, reward,
      Wenc, wih0, whh0, wih1, whh1,
      ws, alw, out, t);
  }
  finalize_kernel<<<(2*HB+255)/256, 256, 0, stream>>>(ws, out);
}